// Round 1
// baseline (798.143 us; speedup 1.0000x reference)
//
#include <hip/hip_runtime.h>

// SingleLSTM: B=32768, T=28, INPUT=28, HIDDEN=128, LABELS=10, fp32 in/out.
// Strategy: per-block recurrence over all 28 steps (batch rows independent).
// 2048 blocks x 512 threads; block owns 16 batch rows; wave w owns gate cols
// [64w, 64w+64). W held in VGPRs as pre-split bf16 (hi+lo) B-fragments.
// Split-precision MFMA: x-part 2 terms (xh*Wh + xl*Wh), h-part 3 terms
// (hh*Wh + hl*Wh + hh*Wl) -> ~2^-17 effective precision in gates.

typedef __bf16 bf16x8 __attribute__((ext_vector_type(8)));
typedef float f32x4 __attribute__((ext_vector_type(4)));

#define HSTRIDE 136   // 128 + 8 pad (bf16) -> 272B row stride, 2-way LDS access (free)
#define GSTRIDE 516   // 512 + 4 pad (f32)  -> 2-way LDS access (free)

__device__ __forceinline__ unsigned short bf16_rn(float f) {
    unsigned u = __float_as_uint(f);
    unsigned r = u + 0x7FFFu + ((u >> 16) & 1u);
    return (unsigned short)(r >> 16);
}

__device__ __forceinline__ void split_bf16(float f, unsigned short& hi, unsigned short& lo) {
    hi = bf16_rn(f);
    float fh = __uint_as_float(((unsigned)hi) << 16);
    lo = bf16_rn(f - fh);   // exact residual, then RN -> total err ~2^-18
}

__device__ __forceinline__ __bf16 us_to_bf(unsigned short u) {
    union { unsigned short s; __bf16 b; } z; z.s = u; return z.b;
}

__device__ __forceinline__ float fast_sigmoid(float x) {
    // 1/(1+2^(-x*log2e))
    return __builtin_amdgcn_rcpf(1.0f + __builtin_amdgcn_exp2f(-1.44269504f * x));
}
__device__ __forceinline__ float fast_tanh(float x) {
    // 1 - 2/(2^(2x*log2e)+1); saturates correctly at +/-inf
    float e = __builtin_amdgcn_exp2f(2.88539008f * x);
    return 1.0f - 2.0f * __builtin_amdgcn_rcpf(e + 1.0f);
}

__global__ __launch_bounds__(512, 2)
void lstm_persist(const float* __restrict__ x,      // [B][28][28]
                  const float* __restrict__ W,      // [156][512]
                  const float* __restrict__ b,      // [512]
                  const float* __restrict__ Wfc,    // [128][10]
                  const float* __restrict__ bfc,    // [10]
                  float* __restrict__ out)          // [B][10]
{
    __shared__ unsigned short h_hi[16 * HSTRIDE];
    __shared__ unsigned short h_lo[16 * HSTRIDE];
    __shared__ float gact[16 * GSTRIDE];

    const int tid  = threadIdx.x;
    const int wave = tid >> 6;
    const int lane = tid & 63;
    const int m16  = lane & 15;
    const int quad = lane >> 4;
    const int row_base = blockIdx.x * 16;
    const int gate = wave >> 1;   // 0:i 1:j 2:f 3:o

    // zero initial h state (c lives in registers, zeroed below)
    for (int i = tid; i < 16 * HSTRIDE; i += 512) { h_hi[i] = 0; h_lo[i] = 0; }

    // ---- Load W fragments into registers (B-operand layout), split hi/lo ----
    // B-frag for 16x16x32: lane holds B[k = quad*8+j][n = lane&15], j=0..7.
    // kstep 0 = x rows (k<28, rest zero); ksteps 1..4 = h rows 28+32*(ks-1)+...
    bf16x8 Whi[5][4];
    bf16x8 Wlo[4][4];   // lo only for the h ksteps (index ks-1)
    float bias[4];
    #pragma unroll
    for (int nt = 0; nt < 4; nt++) {
        const int col = wave * 64 + nt * 16 + m16;
        float bb = b[col];
        if (gate == 2) bb += 1.0f;   // FORGET_BIAS folded into f-gate bias
        bias[nt] = bb;
        #pragma unroll
        for (int ks = 0; ks < 5; ks++) {
            bf16x8 h8, l8;
            #pragma unroll
            for (int j = 0; j < 8; j++) {
                int kk = quad * 8 + j;
                int k  = (ks == 0) ? kk : (28 + (ks - 1) * 32 + kk);
                float v = 0.0f;
                if (ks != 0 || kk < 28) v = W[k * 512 + col];
                unsigned short hi, lo; split_bf16(v, hi, lo);
                h8[j] = us_to_bf(hi); l8[j] = us_to_bf(lo);
            }
            Whi[ks][nt] = h8;
            if (ks > 0) Wlo[ks - 1][nt] = l8;
        }
    }
    __syncthreads();

    float creg[4] = {0.0f, 0.0f, 0.0f, 0.0f};   // persistent c, 4 elems/thread

    for (int t = 0; t < 28; t++) {
        // ---- Phase A: gates = [x_t | h] @ W + b, per-wave 64 cols ----
        // x A-frag: lane holds x[row=m16][k=quad*8+j] (k<28), split hi/lo
        bf16x8 axh, axl;
        {
            const float* xr = x + (size_t)(row_base + m16) * 784 + t * 28;
            float4 v0 = *(const float4*)(xr + quad * 8);
            float4 v1 = make_float4(0.f, 0.f, 0.f, 0.f);
            if (quad < 3) v1 = *(const float4*)(xr + quad * 8 + 4);
            float vals[8] = {v0.x, v0.y, v0.z, v0.w, v1.x, v1.y, v1.z, v1.w};
            #pragma unroll
            for (int j = 0; j < 8; j++) {
                unsigned short hi, lo; split_bf16(vals[j], hi, lo);
                axh[j] = us_to_bf(hi); axl[j] = us_to_bf(lo);
            }
        }
        // h A-frags from LDS (bf16 hi/lo), ds_read_b128 each
        bf16x8 ahh[4], ahl[4];
        #pragma unroll
        for (int ks = 0; ks < 4; ks++) {
            const int off = m16 * HSTRIDE + ks * 32 + quad * 8;
            ahh[ks] = *(const bf16x8*)(h_hi + off);
            ahl[ks] = *(const bf16x8*)(h_lo + off);
        }

        f32x4 acc[4];
        #pragma unroll
        for (int nt = 0; nt < 4; nt++)
            acc[nt] = (f32x4){bias[nt], bias[nt], bias[nt], bias[nt]};

        #pragma unroll
        for (int nt = 0; nt < 4; nt++)
            acc[nt] = __builtin_amdgcn_mfma_f32_16x16x32_bf16(axh, Whi[0][nt], acc[nt], 0, 0, 0);
        #pragma unroll
        for (int nt = 0; nt < 4; nt++)
            acc[nt] = __builtin_amdgcn_mfma_f32_16x16x32_bf16(axl, Whi[0][nt], acc[nt], 0, 0, 0);
        #pragma unroll
        for (int ks = 0; ks < 4; ks++) {
            #pragma unroll
            for (int nt = 0; nt < 4; nt++) {
                acc[nt] = __builtin_amdgcn_mfma_f32_16x16x32_bf16(ahh[ks], Whi[ks + 1][nt], acc[nt], 0, 0, 0);
                acc[nt] = __builtin_amdgcn_mfma_f32_16x16x32_bf16(ahl[ks], Whi[ks + 1][nt], acc[nt], 0, 0, 0);
                acc[nt] = __builtin_amdgcn_mfma_f32_16x16x32_bf16(ahh[ks], Wlo[ks][nt], acc[nt], 0, 0, 0);
            }
        }

        // per-wave uniform activation, write to LDS
        // C/D layout: col = lane&15, row = quad*4 + r
        #pragma unroll
        for (int nt = 0; nt < 4; nt++) {
            const int col = wave * 64 + nt * 16 + m16;
            #pragma unroll
            for (int r = 0; r < 4; r++) {
                float g = acc[nt][r];
                float a = (gate == 1) ? fast_tanh(g) : fast_sigmoid(g);
                gact[(quad * 4 + r) * GSTRIDE + col] = a;
            }
        }
        __syncthreads();

        // ---- Phase B: elementwise c/h update, 4 elems per thread ----
        #pragma unroll
        for (int e = 0; e < 4; e++) {
            const int idx = e * 512 + tid;
            const int row = idx >> 7, cc = idx & 127;
            const float* gr = gact + row * GSTRIDE;
            float iv = gr[cc], jv = gr[128 + cc], fv = gr[256 + cc], ov = gr[384 + cc];
            float nc = creg[e] * fv + iv * jv;
            creg[e] = nc;
            float h = fast_tanh(nc) * ov;
            unsigned short hi, lo; split_bf16(h, hi, lo);
            h_hi[row * HSTRIDE + cc] = hi;
            h_lo[row * HSTRIDE + cc] = lo;
        }
        __syncthreads();
    }

    // ---- Final FC: logits = h @ Wfc + bfc (fp32) ----
    if (tid < 160) {
        const int row = tid / 10, lab = tid % 10;
        float acc = bfc[lab];
        #pragma unroll 8
        for (int k = 0; k < 128; k++) {
            float h = __uint_as_float(((unsigned)h_hi[row * HSTRIDE + k]) << 16)
                    + __uint_as_float(((unsigned)h_lo[row * HSTRIDE + k]) << 16);
            acc += h * Wfc[k * 10 + lab];
        }
        out[(size_t)(row_base + row) * 10 + lab] = acc;   // contiguous: offset = row_base*10 + tid
    }
}

extern "C" void kernel_launch(void* const* d_in, const int* in_sizes, int n_in,
                              void* d_out, int out_size, void* d_ws, size_t ws_size,
                              hipStream_t stream) {
    const float* x   = (const float*)d_in[0];
    const float* W   = (const float*)d_in[1];
    const float* b   = (const float*)d_in[2];
    const float* Wfc = (const float*)d_in[3];
    const float* bfc = (const float*)d_in[4];
    float* out = (float*)d_out;

    const int B = in_sizes[0] / (28 * 28);   // 32768
    const int blocks = B / 16;               // 2048
    lstm_persist<<<blocks, 512, 0, stream>>>(x, W, b, Wfc, bfc, out);
}

// Round 2
// 626.267 us; speedup vs baseline: 1.2744x; 1.2744x over previous
//
#include <hip/hip_runtime.h>

// SingleLSTM: B=32768, T=28, INPUT=28, HIDDEN=128, LABELS=10, fp32.
// R2: wave owns 16 HIDDEN cols x all 4 gates -> c/h update fully per-lane,
// ONE barrier per step (double-buffered h in LDS). 32 rows/block (1024 blocks).
// W resident in regs as split bf16 (hi+lo). x prefetched one step ahead.

typedef __bf16 bf16x8 __attribute__((ext_vector_type(8)));
typedef float f32x4 __attribute__((ext_vector_type(4)));

#define HSTRIDE 136            // 128 + 8 pad shorts; 272 B row, keeps 16B alignment
#define L2E 1.44269504f

__device__ __forceinline__ unsigned short bf16_rn(float f) {
    unsigned u = __float_as_uint(f);
    unsigned r = u + 0x7FFFu + ((u >> 16) & 1u);
    return (unsigned short)(r >> 16);
}
__device__ __forceinline__ void split_bf16(float f, unsigned short& hi, unsigned short& lo) {
    hi = bf16_rn(f);
    float fh = __uint_as_float(((unsigned)hi) << 16);
    lo = bf16_rn(f - fh);
}
__device__ __forceinline__ __bf16 us_to_bf(unsigned short u) {
    union { unsigned short s; __bf16 b; } z; z.s = u; return z.b;
}

__global__ __launch_bounds__(512, 2)
void lstm_r2(const float* __restrict__ x,      // [B][28][28]
             const float* __restrict__ W,      // [156][512]
             const float* __restrict__ b,      // [512]
             const float* __restrict__ Wfc,    // [128][10]
             const float* __restrict__ bfc,    // [10]
             float* __restrict__ out)          // [B][10]
{
    __shared__ __align__(16) unsigned short h_hi[2][32 * HSTRIDE];
    __shared__ __align__(16) unsigned short h_lo[2][32 * HSTRIDE];

    const int tid  = threadIdx.x;
    const int wave = tid >> 6;
    const int lane = tid & 63;
    const int m16  = lane & 15;
    const int quad = lane >> 4;
    const int rbase = blockIdx.x * 32;
    const int hc = wave * 16 + m16;     // this lane's hidden column

    // zero initial h (buffer 0)
    for (int i = tid; i < 32 * HSTRIDE; i += 512) { h_hi[0][i] = 0; h_lo[0][i] = 0; }

    // ---- W fragments: B-layout lane holds B[k=quad*8+j][n=m16-of-col-tile] ----
    // gate g tile cols: g*128 + wave*16 + m16
    bf16x8 Wxh[4];                 // x rows (k<28, rest 0), hi only
    bf16x8 Whh[4][4], Whl[4][4];   // h rows, [ks][gate], hi+lo
    float bias[4];
    #pragma unroll
    for (int g = 0; g < 4; g++) {
        const int col = g * 128 + wave * 16 + m16;
        bias[g] = b[col] + (g == 2 ? 1.0f : 0.0f);   // FORGET_BIAS folded
        bf16x8 h8;
        #pragma unroll
        for (int j = 0; j < 8; j++) {
            int kk = quad * 8 + j;
            float v = (kk < 28) ? W[kk * 512 + col] : 0.0f;
            unsigned short hi, lo; split_bf16(v, hi, lo);
            h8[j] = us_to_bf(hi);
        }
        Wxh[g] = h8;
        #pragma unroll
        for (int ks = 0; ks < 4; ks++) {
            bf16x8 hh, ll;
            #pragma unroll
            for (int j = 0; j < 8; j++) {
                int k = 28 + ks * 32 + quad * 8 + j;
                float v = W[k * 512 + col];
                unsigned short hi, lo; split_bf16(v, hi, lo);
                hh[j] = us_to_bf(hi); ll[j] = us_to_bf(lo);
            }
            Whh[ks][g] = hh; Whl[ks][g] = ll;
        }
    }
    __syncthreads();

    float creg[8] = {0, 0, 0, 0, 0, 0, 0, 0};

    // preload x for t=0 (A-layout: lane holds x[row=m16(+16mt)][k=quad*8+j])
    float4 xa[2], xb[2];
    #pragma unroll
    for (int mt = 0; mt < 2; mt++) {
        const float* xr = x + (size_t)(rbase + mt * 16 + m16) * 784;
        xa[mt] = *(const float4*)(xr + quad * 8);
        xb[mt] = (quad < 3) ? *(const float4*)(xr + quad * 8 + 4)
                            : make_float4(0.f, 0.f, 0.f, 0.f);
    }

    int buf = 0;
    for (int t = 0; t < 28; t++) {
        // convert current raw x -> frags
        bf16x8 axh[2], axl[2];
        #pragma unroll
        for (int mt = 0; mt < 2; mt++) {
            float vals[8] = {xa[mt].x, xa[mt].y, xa[mt].z, xa[mt].w,
                             xb[mt].x, xb[mt].y, xb[mt].z, xb[mt].w};
            #pragma unroll
            for (int j = 0; j < 8; j++) {
                unsigned short hi, lo; split_bf16(vals[j], hi, lo);
                axh[mt][j] = us_to_bf(hi); axl[mt][j] = us_to_bf(lo);
            }
        }
        // prefetch x for t+1 (long-latency; covered by the MFMA section)
        {
            const int tn = (t < 27) ? t + 1 : t;
            #pragma unroll
            for (int mt = 0; mt < 2; mt++) {
                const float* xr = x + (size_t)(rbase + mt * 16 + m16) * 784 + tn * 28;
                xa[mt] = *(const float4*)(xr + quad * 8);
                if (quad < 3) xb[mt] = *(const float4*)(xr + quad * 8 + 4);
            }
        }

        f32x4 acc[2][4];
        #pragma unroll
        for (int mt = 0; mt < 2; mt++)
            #pragma unroll
            for (int g = 0; g < 4; g++)
                acc[mt][g] = (f32x4){bias[g], bias[g], bias[g], bias[g]};

        // h-part MFMAs (3 split-precision terms), streamed per (ks, mt)
        #pragma unroll
        for (int ks = 0; ks < 4; ks++) {
            #pragma unroll
            for (int mt = 0; mt < 2; mt++) {
                const int off = (mt * 16 + m16) * HSTRIDE + ks * 32 + quad * 8;
                bf16x8 ahh = *(const bf16x8*)(&h_hi[buf][off]);
                bf16x8 ahl = *(const bf16x8*)(&h_lo[buf][off]);
                #pragma unroll
                for (int g = 0; g < 4; g++) {
                    acc[mt][g] = __builtin_amdgcn_mfma_f32_16x16x32_bf16(ahh, Whh[ks][g], acc[mt][g], 0, 0, 0);
                    acc[mt][g] = __builtin_amdgcn_mfma_f32_16x16x32_bf16(ahl, Whh[ks][g], acc[mt][g], 0, 0, 0);
                    acc[mt][g] = __builtin_amdgcn_mfma_f32_16x16x32_bf16(ahh, Whl[ks][g], acc[mt][g], 0, 0, 0);
                }
            }
        }
        // x-part MFMAs (2 terms)
        #pragma unroll
        for (int mt = 0; mt < 2; mt++)
            #pragma unroll
            for (int g = 0; g < 4; g++) {
                acc[mt][g] = __builtin_amdgcn_mfma_f32_16x16x32_bf16(axh[mt], Wxh[g], acc[mt][g], 0, 0, 0);
                acc[mt][g] = __builtin_amdgcn_mfma_f32_16x16x32_bf16(axl[mt], Wxh[g], acc[mt][g], 0, 0, 0);
            }

        // ---- per-lane c/h update; C/D: row = quad*4+r (+16mt), col = hc ----
        #pragma unroll
        for (int mt = 0; mt < 2; mt++) {
            #pragma unroll
            for (int r = 0; r < 4; r++) {
                float gi = acc[mt][0][r], gj = acc[mt][1][r];
                float gf = acc[mt][2][r], go = acc[mt][3][r];
                // sig(i)*tanh(j) = (e2j-1) / ((1+ei)*(e2j+1))
                float ei  = __builtin_amdgcn_exp2f(-L2E * gi);
                float e2j = __builtin_amdgcn_exp2f(2.0f * L2E * gj);
                float ij  = (e2j - 1.0f) * __builtin_amdgcn_rcpf((1.0f + ei) * (e2j + 1.0f));
                float sf  = __builtin_amdgcn_rcpf(1.0f + __builtin_amdgcn_exp2f(-L2E * gf));
                float nc  = creg[mt * 4 + r] * sf + ij;
                creg[mt * 4 + r] = nc;
                // tanh(nc)*sig(o) = (e2c-1) / ((e2c+1)*(1+eo))
                float e2c = __builtin_amdgcn_exp2f(2.0f * L2E * nc);
                float eo  = __builtin_amdgcn_exp2f(-L2E * go);
                float hv  = (e2c - 1.0f) * __builtin_amdgcn_rcpf((e2c + 1.0f) * (1.0f + eo));
                unsigned short hi, lo; split_bf16(hv, hi, lo);
                const int woff = (mt * 16 + quad * 4 + r) * HSTRIDE + hc;
                h_hi[buf ^ 1][woff] = hi;
                h_lo[buf ^ 1][woff] = lo;
            }
        }
        __syncthreads();
        buf ^= 1;
    }

    // ---- FC epilogue: logits = h @ Wfc + bfc ----
    if (tid < 320) {
        const int row = tid / 10, lab = tid % 10;
        float acc = bfc[lab];
        #pragma unroll 8
        for (int k = 0; k < 128; k++) {
            float h = __uint_as_float(((unsigned)h_hi[buf][row * HSTRIDE + k]) << 16)
                    + __uint_as_float(((unsigned)h_lo[buf][row * HSTRIDE + k]) << 16);
            acc += h * Wfc[k * 10 + lab];
        }
        out[(size_t)(rbase + row) * 10 + lab] = acc;
    }
}

extern "C" void kernel_launch(void* const* d_in, const int* in_sizes, int n_in,
                              void* d_out, int out_size, void* d_ws, size_t ws_size,
                              hipStream_t stream) {
    const float* x   = (const float*)d_in[0];
    const float* W   = (const float*)d_in[1];
    const float* b   = (const float*)d_in[2];
    const float* Wfc = (const float*)d_in[3];
    const float* bfc = (const float*)d_in[4];
    float* out = (float*)d_out;

    const int B = in_sizes[0] / (28 * 28);   // 32768
    const int blocks = B / 32;               // 1024
    lstm_r2<<<blocks, 512, 0, stream>>>(x, W, b, Wfc, bfc, out);
}

// Round 3
// 519.897 us; speedup vs baseline: 1.5352x; 1.2046x over previous
//
#include <hip/hip_runtime.h>

// SingleLSTM: B=32768, T=28, INPUT=28, HIDDEN=128, LABELS=10, fp32.
// R3: wave owns 16 hidden cols x all 4 gates (per-lane c/h update, one
// barrier/step). W-lo term dropped (W bf16-hi only: 80 VGPRs, no spills).
// h kept hi+lo. x staged through LDS pre-split in A-frag order by all
// threads cooperatively (was 8x duplicated per-wave work).

typedef __bf16 bf16x8 __attribute__((ext_vector_type(8)));
typedef float f32x4 __attribute__((ext_vector_type(4)));

#define HSTRIDE 136   // shorts; 272B row: 16B-aligned, 2-way (free) LDS access
#define L2E 1.44269504f

__device__ __forceinline__ unsigned short bf16_rn(float f) {
    unsigned u = __float_as_uint(f);
    unsigned r = u + 0x7FFFu + ((u >> 16) & 1u);
    return (unsigned short)(r >> 16);
}
__device__ __forceinline__ void split_bf16(float f, unsigned short& hi, unsigned short& lo) {
    hi = bf16_rn(f);
    float fh = __uint_as_float(((unsigned)hi) << 16);
    lo = bf16_rn(f - fh);
}
__device__ __forceinline__ __bf16 us_to_bf(unsigned short u) {
    union { unsigned short s; __bf16 b; } z; z.s = u; return z.b;
}

__global__ __launch_bounds__(512, 2)
void lstm_r3(const float* __restrict__ x,      // [B][28][28]
             const float* __restrict__ W,      // [156][512]
             const float* __restrict__ b,      // [512]
             const float* __restrict__ Wfc,    // [128][10]
             const float* __restrict__ bfc,    // [10]
             float* __restrict__ out)          // [B][10]
{
    __shared__ __align__(16) unsigned short h_hi[2][32 * HSTRIDE];
    __shared__ __align__(16) unsigned short h_lo[2][32 * HSTRIDE];
    // x staged pre-split in A-frag order: [buf][mt][kb*128 + r*8 + kk]
    __shared__ __align__(16) unsigned short xs_hi[2][2][512];
    __shared__ __align__(16) unsigned short xs_lo[2][2][512];

    const int tid  = threadIdx.x;
    const int wave = tid >> 6;
    const int lane = tid & 63;
    const int m16  = lane & 15;
    const int quad = lane >> 4;
    const int rbase = blockIdx.x * 32;
    const int hc = wave * 16 + m16;     // this lane's hidden column

    // ---- init: zero h buf0 and both xs bufs (k>=28 slots must stay 0) ----
    for (int i = tid; i < 32 * HSTRIDE; i += 512) { h_hi[0][i] = 0; h_lo[0][i] = 0; }
    for (int i = tid; i < 2 * 2 * 512; i += 512) {
        ((unsigned short*)xs_hi)[i] = 0; ((unsigned short*)xs_lo)[i] = 0;
    }

    // per-thread x staging slot (fixed for all steps): element idx, idx+512
    // covers 32 rows x 28 k = 896 elements
    const int sidx  = tid;                 // first element
    const int srow  = sidx / 28, sk = sidx % 28;
    const int smt   = srow >> 4;
    const int soff  = (sk >> 3) * 128 + (srow & 15) * 8 + (sk & 7);
    const int sidx2 = tid + 512;           // second element (tid < 384 only)
    const int srow2 = sidx2 / 28, sk2 = sidx2 % 28;
    const int smt2  = srow2 >> 4;
    const int soff2 = (sk2 >> 3) * 128 + (srow2 & 15) * 8 + (sk2 & 7);
    const float* xp  = x + (size_t)(rbase + srow)  * 784 + sk;
    const float* xp2 = x + (size_t)(rbase + srow2) * 784 + sk2;

    // ---- W fragments (hi only): B-layout lane holds B[k=quad*8+j][col] ----
    bf16x8 Wxh[4];          // x rows (k<28, rest 0)
    bf16x8 Whh[4][4];       // [ks][gate]
    float bias[4];
    #pragma unroll
    for (int g = 0; g < 4; g++) {
        const int col = g * 128 + wave * 16 + m16;
        bias[g] = b[col] + (g == 2 ? 1.0f : 0.0f);   // FORGET_BIAS folded
        bf16x8 h8;
        #pragma unroll
        for (int j = 0; j < 8; j++) {
            int kk = quad * 8 + j;
            h8[j] = us_to_bf((kk < 28) ? bf16_rn(W[kk * 512 + col]) : (unsigned short)0);
        }
        Wxh[g] = h8;
        #pragma unroll
        for (int ks = 0; ks < 4; ks++) {
            bf16x8 hh;
            #pragma unroll
            for (int j = 0; j < 8; j++)
                hh[j] = us_to_bf(bf16_rn(W[(28 + ks * 32 + quad * 8 + j) * 512 + col]));
            Whh[ks][g] = hh;
        }
    }

    // ---- stage x for t=0 into xs[0] ----
    {
        float v = *xp;
        unsigned short hi, lo; split_bf16(v, hi, lo);
        xs_hi[0][smt][soff] = hi; xs_lo[0][smt][soff] = lo;
        if (tid < 384) {
            float v2 = *xp2;
            unsigned short hi2, lo2; split_bf16(v2, hi2, lo2);
            xs_hi[0][smt2][soff2] = hi2; xs_lo[0][smt2][soff2] = lo2;
        }
    }
    __syncthreads();

    float creg[8] = {0, 0, 0, 0, 0, 0, 0, 0};
    int buf = 0;

    for (int t = 0; t < 28; t++) {
        const int nb = buf ^ 1;

        // ---- stage x for t+1 (skipped on last step); latency hides under MFMAs
        if (t < 27) {
            float v = xp[(t + 1) * 28];
            unsigned short hi, lo; split_bf16(v, hi, lo);
            xs_hi[nb][smt][soff] = hi; xs_lo[nb][smt][soff] = lo;
            if (tid < 384) {
                float v2 = xp2[(t + 1) * 28];
                unsigned short hi2, lo2; split_bf16(v2, hi2, lo2);
                xs_hi[nb][smt2][soff2] = hi2; xs_lo[nb][smt2][soff2] = lo2;
            }
        }

        // ---- read A-frags from LDS ----
        const int foff = quad * 128 + m16 * 8;
        bf16x8 axh[2], axl[2], ahh[4][2], ahl[4][2];
        #pragma unroll
        for (int mt = 0; mt < 2; mt++) {
            axh[mt] = *(const bf16x8*)(&xs_hi[buf][mt][foff]);
            axl[mt] = *(const bf16x8*)(&xs_lo[buf][mt][foff]);
        }
        #pragma unroll
        for (int ks = 0; ks < 4; ks++)
            #pragma unroll
            for (int mt = 0; mt < 2; mt++) {
                const int off = (mt * 16 + m16) * HSTRIDE + ks * 32 + quad * 8;
                ahh[ks][mt] = *(const bf16x8*)(&h_hi[buf][off]);
                ahl[ks][mt] = *(const bf16x8*)(&h_lo[buf][off]);
            }

        // ---- MFMAs: gates = [x|h] @ W + b ----
        f32x4 acc[2][4];
        #pragma unroll
        for (int mt = 0; mt < 2; mt++)
            #pragma unroll
            for (int g = 0; g < 4; g++)
                acc[mt][g] = (f32x4){bias[g], bias[g], bias[g], bias[g]};

        #pragma unroll
        for (int mt = 0; mt < 2; mt++)
            #pragma unroll
            for (int g = 0; g < 4; g++) {
                acc[mt][g] = __builtin_amdgcn_mfma_f32_16x16x32_bf16(axh[mt], Wxh[g], acc[mt][g], 0, 0, 0);
                acc[mt][g] = __builtin_amdgcn_mfma_f32_16x16x32_bf16(axl[mt], Wxh[g], acc[mt][g], 0, 0, 0);
            }
        #pragma unroll
        for (int ks = 0; ks < 4; ks++)
            #pragma unroll
            for (int mt = 0; mt < 2; mt++)
                #pragma unroll
                for (int g = 0; g < 4; g++) {
                    acc[mt][g] = __builtin_amdgcn_mfma_f32_16x16x32_bf16(ahh[ks][mt], Whh[ks][g], acc[mt][g], 0, 0, 0);
                    acc[mt][g] = __builtin_amdgcn_mfma_f32_16x16x32_bf16(ahl[ks][mt], Whh[ks][g], acc[mt][g], 0, 0, 0);
                }

        // ---- per-lane c/h update; C/D: row = mt*16 + quad*4 + r, col = hc ----
        #pragma unroll
        for (int mt = 0; mt < 2; mt++) {
            #pragma unroll
            for (int r = 0; r < 4; r++) {
                float gi = acc[mt][0][r], gj = acc[mt][1][r];
                float gf = acc[mt][2][r], go = acc[mt][3][r];
                float ei  = __builtin_amdgcn_exp2f(-L2E * gi);
                float e2j = __builtin_amdgcn_exp2f(2.0f * L2E * gj);
                float ij  = (e2j - 1.0f) * __builtin_amdgcn_rcpf((1.0f + ei) * (e2j + 1.0f));
                float sf  = __builtin_amdgcn_rcpf(1.0f + __builtin_amdgcn_exp2f(-L2E * gf));
                float nc  = creg[mt * 4 + r] * sf + ij;
                creg[mt * 4 + r] = nc;
                float e2c = __builtin_amdgcn_exp2f(2.0f * L2E * nc);
                float eo  = __builtin_amdgcn_exp2f(-L2E * go);
                float hv  = (e2c - 1.0f) * __builtin_amdgcn_rcpf((e2c + 1.0f) * (1.0f + eo));
                unsigned short hi, lo; split_bf16(hv, hi, lo);
                const int woff = (mt * 16 + quad * 4 + r) * HSTRIDE + hc;
                h_hi[nb][woff] = hi;
                h_lo[nb][woff] = lo;
            }
        }
        __syncthreads();
        buf = nb;
    }

    // ---- FC epilogue: logits = h @ Wfc + bfc ----
    if (tid < 320) {
        const int row = tid / 10, lab = tid % 10;
        float acc = bfc[lab];
        #pragma unroll 8
        for (int k = 0; k < 128; k++) {
            float h = __uint_as_float(((unsigned)h_hi[buf][row * HSTRIDE + k]) << 16)
                    + __uint_as_float(((unsigned)h_lo[buf][row * HSTRIDE + k]) << 16);
            acc += h * Wfc[k * 10 + lab];
        }
        out[(size_t)(rbase + row) * 10 + lab] = acc;
    }
}

extern "C" void kernel_launch(void* const* d_in, const int* in_sizes, int n_in,
                              void* d_out, int out_size, void* d_ws, size_t ws_size,
                              hipStream_t stream) {
    const float* x   = (const float*)d_in[0];
    const float* W   = (const float*)d_in[1];
    const float* b   = (const float*)d_in[2];
    const float* Wfc = (const float*)d_in[3];
    const float* bfc = (const float*)d_in[4];
    float* out = (float*)d_out;

    const int B = in_sizes[0] / (28 * 28);   // 32768
    const int blocks = B / 32;               // 1024
    lstm_r3<<<blocks, 512, 0, stream>>>(x, W, b, Wfc, bfc, out);
}

// Round 4
// 389.069 us; speedup vs baseline: 2.0514x; 1.3363x over previous
//
#include <hip/hip_runtime.h>

// SingleLSTM: B=32768, T=28, INPUT=28, HIDDEN=128, LABELS=10, fp32.
// R4: all-fp16 datapath (values are small-range; fp16 quant err 2^-11 is
// 4x better than bf16-hi which already passed) -> single-term MFMAs, no
// split-precision machinery. Wave owns 16 hidden cols x 4 gates; per-lane
// c/h update; 64 rows/block (512 blocks), one barrier/step, h fp16
// double-buffered in LDS, x prefetched into registers one step ahead.

typedef _Float16 f16x8 __attribute__((ext_vector_type(8)));
typedef float f32x4 __attribute__((ext_vector_type(4)));

#define HSTRIDE 136   // f16 elems; 272 B row: 16B-aligned, 2-way (free) LDS
#define L2E 1.44269504f

__device__ __forceinline__ float fast_exp2(float x) { return __builtin_amdgcn_exp2f(x); }
__device__ __forceinline__ float fast_rcp(float x)  { return __builtin_amdgcn_rcpf(x); }

__global__ __launch_bounds__(512, 2)
void lstm_r4(const float* __restrict__ x,      // [B][28][28]
             const float* __restrict__ W,      // [156][512]
             const float* __restrict__ b,      // [512]
             const float* __restrict__ Wfc,    // [128][10]
             const float* __restrict__ bfc,    // [10]
             float* __restrict__ out)          // [B][10]
{
    __shared__ __align__(16) _Float16 h_s[2][64 * HSTRIDE];

    const int tid  = threadIdx.x;
    const int wave = tid >> 6;
    const int lane = tid & 63;
    const int m16  = lane & 15;
    const int quad = lane >> 4;
    const int rbase = blockIdx.x * 64;
    const int hc = wave * 16 + m16;     // this lane's hidden column

    // zero initial h (buffer 0)
    for (int i = tid; i < 64 * HSTRIDE; i += 512) h_s[0][i] = (_Float16)0.0f;

    // ---- W fragments (fp16), B-layout: lane holds B[k=quad*8+j][col] ----
    f16x8 Wx[4];        // x rows, k<28 (28..31 zero)
    f16x8 Wh[4][4];     // [ks][gate], k = 28 + ks*32 + quad*8 + j
    float bias[4];
    #pragma unroll
    for (int g = 0; g < 4; g++) {
        const int col = g * 128 + wave * 16 + m16;
        bias[g] = b[col] + (g == 2 ? 1.0f : 0.0f);   // FORGET_BIAS folded
        f16x8 w8;
        #pragma unroll
        for (int j = 0; j < 8; j++) {
            int kk = quad * 8 + j;
            w8[j] = (kk < 28) ? (_Float16)W[kk * 512 + col] : (_Float16)0.0f;
        }
        Wx[g] = w8;
        #pragma unroll
        for (int ks = 0; ks < 4; ks++) {
            f16x8 h8;
            #pragma unroll
            for (int j = 0; j < 8; j++)
                h8[j] = (_Float16)W[(28 + ks * 32 + quad * 8 + j) * 512 + col];
            Wh[ks][g] = h8;
        }
    }

    // ---- preload x for t=0, raw fp32 (A-layout: row = mt*16+m16, k = quad*8+j)
    float4 xa[4], xb[4];
    #pragma unroll
    for (int mt = 0; mt < 4; mt++) {
        const float* xr = x + (size_t)(rbase + mt * 16 + m16) * 784;
        xa[mt] = *(const float4*)(xr + quad * 8);
        xb[mt] = (quad < 3) ? *(const float4*)(xr + quad * 8 + 4)
                            : make_float4(0.f, 0.f, 0.f, 0.f);
    }
    __syncthreads();

    float creg[16];
    #pragma unroll
    for (int i = 0; i < 16; i++) creg[i] = 0.0f;

    int buf = 0;
    for (int t = 0; t < 28; t++) {
        const int nb = buf ^ 1;

        // convert current raw x -> fp16 frags
        f16x8 ax[4];
        #pragma unroll
        for (int mt = 0; mt < 4; mt++) {
            ax[mt][0] = (_Float16)xa[mt].x; ax[mt][1] = (_Float16)xa[mt].y;
            ax[mt][2] = (_Float16)xa[mt].z; ax[mt][3] = (_Float16)xa[mt].w;
            ax[mt][4] = (_Float16)xb[mt].x; ax[mt][5] = (_Float16)xb[mt].y;
            ax[mt][6] = (_Float16)xb[mt].z; ax[mt][7] = (_Float16)xb[mt].w;
        }
        // prefetch x for t+1 (hidden under MFMA section)
        {
            const int tn = (t < 27) ? t + 1 : t;
            #pragma unroll
            for (int mt = 0; mt < 4; mt++) {
                const float* xr = x + (size_t)(rbase + mt * 16 + m16) * 784 + tn * 28;
                xa[mt] = *(const float4*)(xr + quad * 8);
                xb[mt] = (quad < 3) ? *(const float4*)(xr + quad * 8 + 4)
                                    : make_float4(0.f, 0.f, 0.f, 0.f);
            }
        }

        // ---- MFMAs: gates = [x|h] @ W + b ----
        f32x4 acc[4][4];
        #pragma unroll
        for (int mt = 0; mt < 4; mt++)
            #pragma unroll
            for (int g = 0; g < 4; g++)
                acc[mt][g] = (f32x4){bias[g], bias[g], bias[g], bias[g]};

        #pragma unroll
        for (int mt = 0; mt < 4; mt++)
            #pragma unroll
            for (int g = 0; g < 4; g++)
                acc[mt][g] = __builtin_amdgcn_mfma_f32_16x16x32_f16(ax[mt], Wx[g], acc[mt][g], 0, 0, 0);

        #pragma unroll
        for (int ks = 0; ks < 4; ks++)
            #pragma unroll
            for (int mt = 0; mt < 4; mt++) {
                const int off = (mt * 16 + m16) * HSTRIDE + ks * 32 + quad * 8;
                f16x8 ah = *(const f16x8*)(&h_s[buf][off]);
                #pragma unroll
                for (int g = 0; g < 4; g++)
                    acc[mt][g] = __builtin_amdgcn_mfma_f32_16x16x32_f16(ah, Wh[ks][g], acc[mt][g], 0, 0, 0);
            }

        // ---- per-lane c/h update; C/D: row = mt*16 + quad*4 + r, col = hc ----
        #pragma unroll
        for (int mt = 0; mt < 4; mt++) {
            #pragma unroll
            for (int r = 0; r < 4; r++) {
                float gi = acc[mt][0][r], gj = acc[mt][1][r];
                float gf = acc[mt][2][r], go = acc[mt][3][r];
                float ei  = fast_exp2(-L2E * gi);
                float e2j = fast_exp2(2.0f * L2E * gj);
                float ij  = (e2j - 1.0f) * fast_rcp((1.0f + ei) * (e2j + 1.0f));
                float sf  = fast_rcp(1.0f + fast_exp2(-L2E * gf));
                float nc  = creg[mt * 4 + r] * sf + ij;
                creg[mt * 4 + r] = nc;
                float e2c = fast_exp2(2.0f * L2E * nc);
                float eo  = fast_exp2(-L2E * go);
                float hv  = (e2c - 1.0f) * fast_rcp((e2c + 1.0f) * (1.0f + eo));
                h_s[nb][(mt * 16 + quad * 4 + r) * HSTRIDE + hc] = (_Float16)hv;
            }
        }
        __syncthreads();
        buf = nb;
    }

    // ---- FC epilogue: logits = h @ Wfc + bfc ----
    for (int i = tid; i < 640; i += 512) {
        const int row = i / 10, lab = i % 10;
        float acc = bfc[lab];
        #pragma unroll 8
        for (int k = 0; k < 128; k++)
            acc += (float)h_s[buf][row * HSTRIDE + k] * Wfc[k * 10 + lab];
        out[(size_t)(rbase + row) * 10 + lab] = acc;
    }
}

extern "C" void kernel_launch(void* const* d_in, const int* in_sizes, int n_in,
                              void* d_out, int out_size, void* d_ws, size_t ws_size,
                              hipStream_t stream) {
    const float* x   = (const float*)d_in[0];
    const float* W   = (const float*)d_in[1];
    const float* b   = (const float*)d_in[2];
    const float* Wfc = (const float*)d_in[3];
    const float* bfc = (const float*)d_in[4];
    float* out = (float*)d_out;

    const int B = in_sizes[0] / (28 * 28);   // 32768
    const int blocks = B / 64;               // 512
    lstm_r4<<<blocks, 512, 0, stream>>>(x, W, b, Wfc, bfc, out);
}